// Round 7
// baseline (457.932 us; speedup 1.0000x reference)
//
#include <hip/hip_runtime.h>
#include <stdint.h>

#define K_DIM 512
#define N_OUT 512
#define BM 128
#define BN 128
#define BK 64
#define NT 8  // K_DIM / BK tiles

typedef __bf16 bf16x8 __attribute__((ext_vector_type(8)));
typedef float f32x4 __attribute__((ext_vector_type(4)));
typedef unsigned short ushort8 __attribute__((ext_vector_type(8)));
typedef unsigned int u32x4 __attribute__((ext_vector_type(4)));

__device__ inline unsigned short f2bf(float f) {
  unsigned u = __float_as_uint(f);
  u += 0x7fffu + ((u >> 16) & 1u);
  return (unsigned short)(u >> 16);
}

// packed f32x2 -> bf16x2 (RNE), 1 VALU instr (no builtin on gfx950 -> inline asm)
__device__ inline unsigned cvt_pk_bf16(float lo, float hi) {
  unsigned r;
  asm("v_cvt_pk_bf16_f32 %0, %1, %2" : "=v"(r) : "v"(lo), "v"(hi));
  return r;
}

// ---------------- tiny prep: W fp32->bf16 + zero s (x untouched!) ---------------
__global__ __launch_bounds__(256) void prep_w_kernel(const float* __restrict__ W,
                                                     unsigned short* __restrict__ wb,
                                                     float* __restrict__ s,
                                                     int n8w, int n8s) {
  int i = blockIdx.x * 256 + threadIdx.x;
  if (i < n8w) {
    const f32x4* sp = (const f32x4*)W + (size_t)i * 2;
    f32x4 a = sp[0], c = sp[1];
    ushort8 o;
    o[0] = f2bf(a[0]); o[1] = f2bf(a[1]); o[2] = f2bf(a[2]); o[3] = f2bf(a[3]);
    o[4] = f2bf(c[0]); o[5] = f2bf(c[1]); o[6] = f2bf(c[2]); o[7] = f2bf(c[3]);
    *(ushort8*)(wb + (size_t)i * 8) = o;
  } else if (i < n8w + n8s) {
    int j = i - n8w;
    f32x4 z = {0.f, 0.f, 0.f, 0.f};
    *(f32x4*)(s + (size_t)j * 8) = z;
    *(f32x4*)(s + (size_t)j * 8 + 4) = z;
  }
}

// ---------------- scatter pre-pass: s[col[e]] += x[e,0] -------------------------
__global__ __launch_bounds__(256) void scatter_s_kernel(const float* __restrict__ x,
                                                        const int* __restrict__ ei,
                                                        float* __restrict__ s, int E) {
  int e = blockIdx.x * 256 + threadIdx.x;
  if (e < E) {
    atomicAdd(s + ei[E + e], x[(size_t)e * K_DIM]);
  }
}

// ---------------- GEMM: counted-vmcnt pipeline + in-kernel A f32->bf16 ----------
// Per tile t: compute(t) from LDS[cur]; cvt A(t+1) regs (compiler waits vmcnt(4),
// keeps B(t+1) flying) -> ds_write LDS[nxt]; issue A(t+2) f32 loads;
// s_waitcnt vmcnt(8) lgkmcnt(0) [B(t+1) done, A(t+2) stays in flight] -> barrier;
// issue B(t+2) glds into LDS[cur] (all waves past barrier = done reading cur).
// ONE barrier per tile; x never round-trips through a bf16 copy in HBM.
__global__ __launch_bounds__(256) void gemm_x32_kernel(
    const float* __restrict__ x, const unsigned short* __restrict__ wb,
    const float* __restrict__ b, const float* __restrict__ s,
    float* __restrict__ out, int M) {
  __shared__ __align__(16) unsigned short Als[2][BM * BK];  // 2 x 16 KB
  __shared__ __align__(16) unsigned short Bls[2][BN * BK];  // 2 x 16 KB

  const int tid = threadIdx.x;
  const int lane = tid & 63;
  const int quad = lane >> 4;
  const int l16 = lane & 15;
  const int waveId = tid >> 6;
  const int wm = (waveId >> 1) * 64;
  const int wn = (waveId & 1) * 64;

  // m204 bijective XCD remap: the 4 column-tiles of one x row-band (256 KB f32,
  // L2-fits) run consecutively on one XCD -> 3 of 4 A reads are L2 hits.
  const int nwg = gridDim.x * gridDim.y;  // 3128, %8 == 0
  int raw = blockIdx.y * gridDim.x + blockIdx.x;
  int q = nwg >> 3, r = nwg & 7;
  int xcd = raw & 7;
  int wg = (xcd < r ? xcd * (q + 1) : r * (q + 1) + (xcd - r) * q) + (raw >> 3);
  const int blockM = (wg >> 2) * BM;  // gridDim.x == N_OUT/BN == 4
  const int blockN = (wg & 3) * BN;

  // staging: thread owns LDS 16B bf16-chunk ch (lane-contiguous per wave, as
  // global_load_lds requires for B); global source chunk XOR-swizzled so the
  // fragment ds_read_b128 is conflict-free. A uses the same chunk map but f32:
  // 8 elems = two f32x4 loads -> cvt_pk -> one ds_write_b128.
  size_t goffA[4], goffB[4];
  int ldsoff[4];
#pragma unroll
  for (int i = 0; i < 4; ++i) {
    int ch = i * 256 + tid;
    int row = ch >> 3;
    int c8 = ch & 7;
    int sc = c8 ^ (row & 7);
    int ga_row = blockM + row;
    if (ga_row > M - 1) ga_row = M - 1;  // clamp tail (masked in epilogue)
    goffA[i] = (size_t)ga_row * K_DIM + sc * 8;          // f32 elements
    goffB[i] = (size_t)(blockN + row) * K_DIM + sc * 8;  // bf16 elements
    ldsoff[i] = ch * 8;
  }

#define BSTAGE(buf, k0)                                                              \
  {                                                                                  \
    _Pragma("unroll") for (int i = 0; i < 4; ++i) {                                  \
      __builtin_amdgcn_global_load_lds(                                              \
          (const __attribute__((address_space(1))) void*)(wb + goffB[i] + (k0)),     \
          (__attribute__((address_space(3))) void*)(&Bls[buf][ldsoff[i]]), 16, 0, 0);\
    }                                                                                \
  }
#define ALOAD(k0)                                                                    \
  {                                                                                  \
    _Pragma("unroll") for (int i = 0; i < 4; ++i) {                                  \
      a0[i] = *(const f32x4*)(x + goffA[i] + (k0));                                  \
      a1[i] = *(const f32x4*)(x + goffA[i] + (k0) + 4);                              \
    }                                                                                \
  }
#define ACVT(buf)                                                                    \
  {                                                                                  \
    _Pragma("unroll") for (int i = 0; i < 4; ++i) {                                  \
      u32x4 w;                                                                       \
      w[0] = cvt_pk_bf16(a0[i][0], a0[i][1]);                                        \
      w[1] = cvt_pk_bf16(a0[i][2], a0[i][3]);                                        \
      w[2] = cvt_pk_bf16(a1[i][0], a1[i][1]);                                        \
      w[3] = cvt_pk_bf16(a1[i][2], a1[i][3]);                                        \
      *(u32x4*)(&Als[buf][ldsoff[i]]) = w;                                           \
    }                                                                                \
  }

  f32x4 acc[4][4] = {};
  f32x4 a0[4], a1[4];

  // ---- prologue: T0 fully staged; T1's loads in flight ----
  ALOAD(0);        // A0 (8 loads)
  BSTAGE(0, 0);    // B0 (4 glds)
  ACVT(0);         // compiler waits A0 (vmcnt(4)); B0 stays in flight
  ALOAD(BK);       // A1 (8 loads)
  BSTAGE(1, BK);   // B1 (4 glds)
  asm volatile("s_waitcnt vmcnt(12) lgkmcnt(0)" ::: "memory");  // B0 done; A1+B1 fly
  __builtin_amdgcn_s_barrier();

#pragma unroll
  for (int t = 0; t < NT; ++t) {
    const int cur = t & 1;
    const int nxt = cur ^ 1;

    // compute tile t from LDS[cur]
#pragma unroll
    for (int ss = 0; ss < 2; ++ss) {
      bf16x8 af[4], bfr[4];
#pragma unroll
      for (int mi = 0; mi < 4; ++mi) {
        int rr = wm + mi * 16 + l16;
        int c = (ss * 4 + quad) ^ (rr & 7);
        af[mi] = *(const bf16x8*)(&Als[cur][rr * BK + c * 8]);
      }
#pragma unroll
      for (int ni = 0; ni < 4; ++ni) {
        int rr = wn + ni * 16 + l16;
        int c = (ss * 4 + quad) ^ (rr & 7);
        bfr[ni] = *(const bf16x8*)(&Bls[cur][rr * BK + c * 8]);
      }
      __builtin_amdgcn_s_setprio(1);
#pragma unroll
      for (int mi = 0; mi < 4; ++mi)
#pragma unroll
        for (int ni = 0; ni < 4; ++ni)
          acc[mi][ni] = __builtin_amdgcn_mfma_f32_16x16x32_bf16(af[mi], bfr[ni], acc[mi][ni], 0, 0, 0);
      __builtin_amdgcn_s_setprio(0);
    }

    if (t + 1 < NT) ACVT(nxt);          // A(t+1) regs -> LDS[nxt] (B-half glds land there too)
    if (t + 2 < NT) ALOAD((t + 2) * BK);  // A(t+2) -> regs, stays in flight across barrier

    if (t + 2 < NT) {
      asm volatile("s_waitcnt vmcnt(8) lgkmcnt(0)" ::: "memory");  // B(t+1) done; A(t+2) flies
    } else if (t + 1 < NT) {
      asm volatile("s_waitcnt vmcnt(0) lgkmcnt(0)" ::: "memory");  // drain tail
    }
    if (t + 1 < NT) __builtin_amdgcn_s_barrier();  // LDS[nxt] ready; all done reading cur

    if (t + 2 < NT) BSTAGE(cur, (t + 2) * BK);  // refill freed buffer
  }
#undef BSTAGE
#undef ALOAD
#undef ACVT

  // epilogue: bias + relu + scatter-add (col 0); C/D layout col=lane&15,
  // row=quad*4+reg (m89/m91). Nontemporal: out never re-read; keep x in caches.
#pragma unroll
  for (int ni = 0; ni < 4; ++ni) {
    int gcol = blockN + wn + ni * 16 + l16;
    float bias = b[gcol];
#pragma unroll
    for (int mi = 0; mi < 4; ++mi) {
#pragma unroll
      for (int rr = 0; rr < 4; ++rr) {
        int grow = blockM + wm + mi * 16 + quad * 4 + rr;
        if (grow < M) {
          float v = acc[mi][ni][rr] + bias;
          v = v > 0.f ? v : 0.f;
          if (gcol == 0) v += s[grow];  // relu first, then scatter-add (matches ref)
          __builtin_nontemporal_store(v, out + (size_t)grow * N_OUT + gcol);
        }
      }
    }
  }
}

// ---------------- fallback: fused-conversion GEMM (if ws too small) -------------
#define LDS_STRIDE 40
__global__ __launch_bounds__(256) void gemm_fused_kernel(
    const float* __restrict__ x, const float* __restrict__ W,
    const float* __restrict__ b, float* __restrict__ out, int M) {
  __shared__ __align__(16) unsigned short Als[BM * LDS_STRIDE];
  __shared__ __align__(16) unsigned short Bls[BN * LDS_STRIDE];
  const int tid = threadIdx.x;
  const int lane = tid & 63;
  const int quad = lane >> 4;
  const int l16 = lane & 15;
  const int waveId = tid >> 6;
  const int wm = (waveId >> 1) * 64;
  const int wn = (waveId & 1) * 64;
  const int blockM = blockIdx.y * BM;
  const int blockN = blockIdx.x * BN;
  f32x4 acc[4][4] = {};
  for (int k0 = 0; k0 < K_DIM; k0 += 32) {
#pragma unroll
    for (int i = 0; i < 4; ++i) {
      int idx = i * 256 + tid;
      int row = idx >> 3;
      int c4 = idx & 7;
      float4 va = make_float4(0.f, 0.f, 0.f, 0.f);
      int grow = blockM + row;
      if (grow < M) va = *(const float4*)(x + (size_t)grow * K_DIM + k0 + c4 * 4);
      ushort4 ha;
      ha.x = f2bf(va.x); ha.y = f2bf(va.y); ha.z = f2bf(va.z); ha.w = f2bf(va.w);
      *(ushort4*)(&Als[row * LDS_STRIDE + c4 * 4]) = ha;
      float4 vb = *(const float4*)(W + (size_t)(blockN + row) * K_DIM + k0 + c4 * 4);
      ushort4 hb;
      hb.x = f2bf(vb.x); hb.y = f2bf(vb.y); hb.z = f2bf(vb.z); hb.w = f2bf(vb.w);
      *(ushort4*)(&Bls[row * LDS_STRIDE + c4 * 4]) = hb;
    }
    __syncthreads();
    bf16x8 af[4], bfr[4];
#pragma unroll
    for (int mi = 0; mi < 4; ++mi)
      af[mi] = *(const bf16x8*)(&Als[(wm + mi * 16 + l16) * LDS_STRIDE + quad * 8]);
#pragma unroll
    for (int ni = 0; ni < 4; ++ni)
      bfr[ni] = *(const bf16x8*)(&Bls[(wn + ni * 16 + l16) * LDS_STRIDE + quad * 8]);
#pragma unroll
    for (int mi = 0; mi < 4; ++mi)
#pragma unroll
      for (int ni = 0; ni < 4; ++ni)
        acc[mi][ni] = __builtin_amdgcn_mfma_f32_16x16x32_bf16(af[mi], bfr[ni], acc[mi][ni], 0, 0, 0);
    __syncthreads();
  }
#pragma unroll
  for (int ni = 0; ni < 4; ++ni) {
    int gcol = blockN + wn + ni * 16 + l16;
    float bias = b[gcol];
#pragma unroll
    for (int mi = 0; mi < 4; ++mi) {
#pragma unroll
      for (int rr = 0; rr < 4; ++rr) {
        int grow = blockM + wm + mi * 16 + quad * 4 + rr;
        if (grow < M) {
          float v = acc[mi][ni][rr] + bias;
          out[(size_t)grow * N_OUT + gcol] = v > 0.f ? v : 0.f;
        }
      }
    }
  }
}

// fallback scatter: out[col[e], 0] += x[e, 0]
__global__ void scatter_kernel(const float* __restrict__ x,
                               const int* __restrict__ ei,
                               float* __restrict__ out, int E) {
  int e = blockIdx.x * 256 + threadIdx.x;
  if (e < E) {
    int c = ei[E + e];
    atomicAdd(out + (size_t)c * N_OUT, x[(size_t)e * K_DIM]);
  }
}

extern "C" void kernel_launch(void* const* d_in, const int* in_sizes, int n_in,
                              void* d_out, int out_size, void* d_ws, size_t ws_size,
                              hipStream_t stream) {
  const float* x = (const float*)d_in[0];
  const int* ei = (const int*)d_in[1];
  const float* W = (const float*)d_in[2];
  const float* b = (const float*)d_in[3];
  float* out = (float*)d_out;

  int M = in_sizes[0] / K_DIM;  // 100000
  int E = in_sizes[1] / 2;      // 100000

  size_t w_elems = (size_t)N_OUT * K_DIM;  // 262,144
  int n8w = (int)(w_elems / 8);            // 32,768
  int n8s = (M + 7) / 8;                   // 12,500
  size_t s_elems = (size_t)n8s * 8;

  // ws layout: wb (bf16) | s (f32) — no xb anymore
  size_t need = w_elems * 2 + s_elems * 4;

  dim3 grid(N_OUT / BN, (M + BM - 1) / BM);  // (4, 782) -> nwg=3128, %8==0

  if (ws_size >= need) {
    unsigned short* wb = (unsigned short*)d_ws;
    float* s = (float*)((char*)d_ws + w_elems * 2);  // 512 KB offset, 16B aligned

    int ptotal = n8w + n8s;
    prep_w_kernel<<<(ptotal + 255) / 256, 256, 0, stream>>>(W, wb, s, n8w, n8s);
    scatter_s_kernel<<<(E + 255) / 256, 256, 0, stream>>>(x, ei, s, E);
    gemm_x32_kernel<<<grid, 256, 0, stream>>>(x, wb, b, s, out, M);
  } else {
    gemm_fused_kernel<<<grid, 256, 0, stream>>>(x, W, b, out, M);
    scatter_kernel<<<(E + 255) / 256, 256, 0, stream>>>(x, ei, out, E);
  }
}

// Round 8
// 430.854 us; speedup vs baseline: 1.0628x; 1.0628x over previous
//
#include <hip/hip_runtime.h>
#include <stdint.h>

#define K_DIM 512
#define N_OUT 512
#define BM 64
#define BN 128
#define BK 64
#define NT 8  // K_DIM / BK tiles

typedef __bf16 bf16x8 __attribute__((ext_vector_type(8)));
typedef float f32x4 __attribute__((ext_vector_type(4)));
typedef unsigned short ushort8 __attribute__((ext_vector_type(8)));

__device__ inline unsigned short f2bf(float f) {
  unsigned u = __float_as_uint(f);
  u += 0x7fffu + ((u >> 16) & 1u);
  return (unsigned short)(u >> 16);
}

// ---------------- prep (grid-stride): cvt x->xb, cvt W->wb, zero s, densify x0 --
__global__ __launch_bounds__(256) void prep_all_kernel(
    const float* __restrict__ x, unsigned short* __restrict__ xb,
    const float* __restrict__ W, unsigned short* __restrict__ wb,
    float* __restrict__ x0, float* __restrict__ s,
    int n8x, int n8w, int n8s) {
  const int stride = gridDim.x * 256;
  const int total = n8x + n8w + n8s;
  for (int i = blockIdx.x * 256 + threadIdx.x; i < total; i += stride) {
    if (i < n8x) {
      const f32x4* sp = (const f32x4*)x + (size_t)i * 2;
      f32x4 a = __builtin_nontemporal_load(sp);
      f32x4 c = __builtin_nontemporal_load(sp + 1);
      ushort8 o;
      o[0] = f2bf(a[0]); o[1] = f2bf(a[1]); o[2] = f2bf(a[2]); o[3] = f2bf(a[3]);
      o[4] = f2bf(c[0]); o[5] = f2bf(c[1]); o[6] = f2bf(c[2]); o[7] = f2bf(c[3]);
      *(ushort8*)(xb + (size_t)i * 8) = o;
      if ((i & 63) == 0) x0[i >> 6] = a[0];  // densify col 0 (row r at chunk 64r)
    } else if (i < n8x + n8w) {
      int j = i - n8x;
      const f32x4* sp = (const f32x4*)W + (size_t)j * 2;
      f32x4 a = sp[0], c = sp[1];
      ushort8 o;
      o[0] = f2bf(a[0]); o[1] = f2bf(a[1]); o[2] = f2bf(a[2]); o[3] = f2bf(a[3]);
      o[4] = f2bf(c[0]); o[5] = f2bf(c[1]); o[6] = f2bf(c[2]); o[7] = f2bf(c[3]);
      *(ushort8*)(wb + (size_t)j * 8) = o;
    } else {
      int j = i - n8x - n8w;
      f32x4 z = {0.f, 0.f, 0.f, 0.f};
      *(f32x4*)(s + (size_t)j * 8) = z;
      *(f32x4*)(s + (size_t)j * 8 + 4) = z;
    }
  }
}

// ---------------- scatter pre-pass: s[col[e]] += x0[e] (coalesced read) ---------
__global__ __launch_bounds__(256) void scatter_s_kernel(const float* __restrict__ x0,
                                                        const int* __restrict__ ei,
                                                        float* __restrict__ s, int E) {
  int e = blockIdx.x * 256 + threadIdx.x;
  if (e < E) {
    atomicAdd(s + ei[E + e], x0[e]);
  }
}

// ---------------- GEMM: R6 counted-vmcnt core at 64x128 tile --------------------
// LDS 48KB -> 3 blocks/CU, 3 waves/SIMD (R6's 64KB gave only 2): barrier-locked
// waves from independent blocks interleave per-SIMD, filling the gaps MfmaUtil
// showed. Ledger: 6 glds/tile/thread (2 A + 4 B); prologue 12 in flight; per tile
// wait vmcnt(6) = tile t done, tile t+1 flying. Swizzle unchanged (row = 128B).
__global__ __launch_bounds__(256, 3) void gemm_bf16_kernel(
    const unsigned short* __restrict__ xb, const unsigned short* __restrict__ wb,
    const float* __restrict__ b, const float* __restrict__ s,
    float* __restrict__ out, int M) {
  __shared__ __align__(16) unsigned short Als[2][BM * BK];  // 2 x 8 KB
  __shared__ __align__(16) unsigned short Bls[2][BN * BK];  // 2 x 16 KB

  const int tid = threadIdx.x;
  const int lane = tid & 63;
  const int quad = lane >> 4;
  const int l16 = lane & 15;
  const int waveId = tid >> 6;
  const int wm = (waveId >> 1) * 32;  // wave tile 32x64 of the 64x128 block
  const int wn = (waveId & 1) * 64;

  // m204 bijective XCD remap (works for nwg%8 != 0 too): the 4 column-tiles of
  // one x row-band run consecutively on one XCD -> A-panel L2-served.
  const int nwg = gridDim.x * gridDim.y;  // 6252
  int raw = blockIdx.y * gridDim.x + blockIdx.x;
  int q = nwg >> 3, r = nwg & 7;
  int xcd = raw & 7;
  int wg = (xcd < r ? xcd * (q + 1) : r * (q + 1) + (xcd - r) * q) + (raw >> 3);
  const int blockM = (wg >> 2) * BM;  // gridDim.x == N_OUT/BN == 4
  const int blockN = (wg & 3) * BN;

  // staging: thread owns lane-contiguous 16B chunks (global_load_lds layout);
  // global source chunk XOR-swizzled -> conflict-free ds_read_b128 (row=128B).
  size_t goffA[2], goffB[4];
  int ldsoffA[2], ldsoffB[4];
#pragma unroll
  for (int i = 0; i < 2; ++i) {
    int ch = i * 256 + tid;      // 512 A-chunks: 64 rows x 8
    int row = ch >> 3;
    int c8 = ch & 7;
    int sc = c8 ^ (row & 7);
    int ga_row = blockM + row;
    if (ga_row > M - 1) ga_row = M - 1;  // clamp tail (masked in epilogue)
    goffA[i] = (size_t)ga_row * K_DIM + sc * 8;
    ldsoffA[i] = ch * 8;
  }
#pragma unroll
  for (int i = 0; i < 4; ++i) {
    int ch = i * 256 + tid;      // 1024 B-chunks: 128 rows x 8
    int row = ch >> 3;
    int c8 = ch & 7;
    int sc = c8 ^ (row & 7);
    goffB[i] = (size_t)(blockN + row) * K_DIM + sc * 8;
    ldsoffB[i] = ch * 8;
  }

#define STAGE(buf, k0)                                                               \
  {                                                                                  \
    _Pragma("unroll") for (int i = 0; i < 2; ++i) {                                  \
      __builtin_amdgcn_global_load_lds(                                              \
          (const __attribute__((address_space(1))) void*)(xb + goffA[i] + (k0)),     \
          (__attribute__((address_space(3))) void*)(&Als[buf][ldsoffA[i]]), 16, 0, 0);\
    }                                                                                \
    _Pragma("unroll") for (int i = 0; i < 4; ++i) {                                  \
      __builtin_amdgcn_global_load_lds(                                              \
          (const __attribute__((address_space(1))) void*)(wb + goffB[i] + (k0)),     \
          (__attribute__((address_space(3))) void*)(&Bls[buf][ldsoffB[i]]), 16, 0, 0);\
    }                                                                                \
  }

  f32x4 acc[2][4] = {};

  // prologue: tiles 0 and 1 in flight (12 loads/thread)
  STAGE(0, 0);
  STAGE(1, BK);

#pragma unroll
  for (int t = 0; t < NT; ++t) {
    // counted wait: tile t's 6 loads done; tile t+1's 6 remain in flight
    if (t < NT - 1) {
      asm volatile("s_waitcnt vmcnt(6)" ::: "memory");
    } else {
      asm volatile("s_waitcnt vmcnt(0)" ::: "memory");
    }
    __builtin_amdgcn_s_barrier();

    const int cur = t & 1;
#pragma unroll
    for (int ss = 0; ss < 2; ++ss) {  // two K=32 steps within BK=64
      bf16x8 af[2], bfr[4];
#pragma unroll
      for (int mi = 0; mi < 2; ++mi) {
        int rr = wm + mi * 16 + l16;
        int c = (ss * 4 + quad) ^ (rr & 7);
        af[mi] = *(const bf16x8*)(&Als[cur][rr * BK + c * 8]);
      }
#pragma unroll
      for (int ni = 0; ni < 4; ++ni) {
        int rr = wn + ni * 16 + l16;
        int c = (ss * 4 + quad) ^ (rr & 7);
        bfr[ni] = *(const bf16x8*)(&Bls[cur][rr * BK + c * 8]);
      }
      __builtin_amdgcn_s_setprio(1);
#pragma unroll
      for (int mi = 0; mi < 2; ++mi)
#pragma unroll
        for (int ni = 0; ni < 4; ++ni)
          acc[mi][ni] = __builtin_amdgcn_mfma_f32_16x16x32_bf16(af[mi], bfr[ni], acc[mi][ni], 0, 0, 0);
      __builtin_amdgcn_s_setprio(0);
    }

    // all waves done reading buf[cur]
    __builtin_amdgcn_s_barrier();
    if (t + 2 < NT) {
      STAGE(cur, (t + 2) * BK);  // refill freed buffer; back to 12 in flight
    }
  }
#undef STAGE

  // epilogue: bias + relu + scatter-add (col 0); C/D layout col=lane&15,
  // row=quad*4+reg (m89/m91). Nontemporal: out never re-read; keep xb in L3.
#pragma unroll
  for (int ni = 0; ni < 4; ++ni) {
    int gcol = blockN + wn + ni * 16 + l16;
    float bias = b[gcol];
#pragma unroll
    for (int mi = 0; mi < 2; ++mi) {
#pragma unroll
      for (int rr = 0; rr < 4; ++rr) {
        int grow = blockM + wm + mi * 16 + quad * 4 + rr;
        if (grow < M) {
          float v = acc[mi][ni][rr] + bias;
          v = v > 0.f ? v : 0.f;
          if (gcol == 0) v += s[grow];  // relu first, then scatter-add (matches ref)
          __builtin_nontemporal_store(v, out + (size_t)grow * N_OUT + gcol);
        }
      }
    }
  }
}

// ---------------- fallback: fused-conversion GEMM (if ws too small) -------------
#define FBM 128
#define FBN 128
#define LDS_STRIDE 40
__global__ __launch_bounds__(256) void gemm_fused_kernel(
    const float* __restrict__ x, const float* __restrict__ W,
    const float* __restrict__ b, float* __restrict__ out, int M) {
  __shared__ __align__(16) unsigned short Als[FBM * LDS_STRIDE];
  __shared__ __align__(16) unsigned short Bls[FBN * LDS_STRIDE];
  const int tid = threadIdx.x;
  const int lane = tid & 63;
  const int quad = lane >> 4;
  const int l16 = lane & 15;
  const int waveId = tid >> 6;
  const int wm = (waveId >> 1) * 64;
  const int wn = (waveId & 1) * 64;
  const int blockM = blockIdx.y * FBM;
  const int blockN = blockIdx.x * FBN;
  f32x4 acc[4][4] = {};
  for (int k0 = 0; k0 < K_DIM; k0 += 32) {
#pragma unroll
    for (int i = 0; i < 4; ++i) {
      int idx = i * 256 + tid;
      int row = idx >> 3;
      int c4 = idx & 7;
      float4 va = make_float4(0.f, 0.f, 0.f, 0.f);
      int grow = blockM + row;
      if (grow < M) va = *(const float4*)(x + (size_t)grow * K_DIM + k0 + c4 * 4);
      ushort4 ha;
      ha.x = f2bf(va.x); ha.y = f2bf(va.y); ha.z = f2bf(va.z); ha.w = f2bf(va.w);
      *(ushort4*)(&Als[row * LDS_STRIDE + c4 * 4]) = ha;
      float4 vb = *(const float4*)(W + (size_t)(blockN + row) * K_DIM + k0 + c4 * 4);
      ushort4 hb;
      hb.x = f2bf(vb.x); hb.y = f2bf(vb.y); hb.z = f2bf(vb.z); hb.w = f2bf(vb.w);
      *(ushort4*)(&Bls[row * LDS_STRIDE + c4 * 4]) = hb;
    }
    __syncthreads();
    bf16x8 af[4], bfr[4];
#pragma unroll
    for (int mi = 0; mi < 4; ++mi)
      af[mi] = *(const bf16x8*)(&Als[(wm + mi * 16 + l16) * LDS_STRIDE + quad * 8]);
#pragma unroll
    for (int ni = 0; ni < 4; ++ni)
      bfr[ni] = *(const bf16x8*)(&Bls[(wn + ni * 16 + l16) * LDS_STRIDE + quad * 8]);
#pragma unroll
    for (int mi = 0; mi < 4; ++mi)
#pragma unroll
      for (int ni = 0; ni < 4; ++ni)
        acc[mi][ni] = __builtin_amdgcn_mfma_f32_16x16x32_bf16(af[mi], bfr[ni], acc[mi][ni], 0, 0, 0);
    __syncthreads();
  }
#pragma unroll
  for (int ni = 0; ni < 4; ++ni) {
    int gcol = blockN + wn + ni * 16 + l16;
    float bias = b[gcol];
#pragma unroll
    for (int mi = 0; mi < 4; ++mi) {
#pragma unroll
      for (int rr = 0; rr < 4; ++rr) {
        int grow = blockM + wm + mi * 16 + quad * 4 + rr;
        if (grow < M) {
          float v = acc[mi][ni][rr] + bias;
          out[(size_t)grow * N_OUT + gcol] = v > 0.f ? v : 0.f;
        }
      }
    }
  }
}

// fallback scatter: out[col[e], 0] += x[e, 0]
__global__ void scatter_kernel(const float* __restrict__ x,
                               const int* __restrict__ ei,
                               float* __restrict__ out, int E) {
  int e = blockIdx.x * 256 + threadIdx.x;
  if (e < E) {
    int c = ei[E + e];
    atomicAdd(out + (size_t)c * N_OUT, x[(size_t)e * K_DIM]);
  }
}

extern "C" void kernel_launch(void* const* d_in, const int* in_sizes, int n_in,
                              void* d_out, int out_size, void* d_ws, size_t ws_size,
                              hipStream_t stream) {
  const float* x = (const float*)d_in[0];
  const int* ei = (const int*)d_in[1];
  const float* W = (const float*)d_in[2];
  const float* b = (const float*)d_in[3];
  float* out = (float*)d_out;

  int M = in_sizes[0] / K_DIM;  // 100000
  int E = in_sizes[1] / 2;      // 100000

  size_t x_elems = (size_t)M * K_DIM;      // 51,200,000
  size_t w_elems = (size_t)N_OUT * K_DIM;  // 262,144
  int n8x = (int)(x_elems / 8);            // 6,400,000
  int n8w = (int)(w_elems / 8);            // 32,768
  int n8s = (M + 7) / 8;                   // 12,500
  size_t s_elems = (size_t)n8s * 8;

  // ws layout: xb (bf16) | wb (bf16) | s (f32) | x0 (f32)
  size_t need = x_elems * 2 + w_elems * 2 + s_elems * 4 + (size_t)M * 4;

  dim3 grid(N_OUT / BN, (M + BM - 1) / BM);  // (4, 1563) -> nwg=6252

  if (ws_size >= need) {
    unsigned short* xb = (unsigned short*)d_ws;
    unsigned short* wb = xb + x_elems;
    float* s = (float*)(wb + w_elems);
    float* x0 = s + s_elems;

    int total = n8x + n8w + n8s;
    int pblk = (total + 255) / 256;
    if (pblk > 2048) pblk = 2048;  // grid-stride
    prep_all_kernel<<<pblk, 256, 0, stream>>>(x, xb, W, wb, x0, s, n8x, n8w, n8s);
    scatter_s_kernel<<<(E + 255) / 256, 256, 0, stream>>>(x0, ei, s, E);
    gemm_bf16_kernel<<<grid, 256, 0, stream>>>(xb, wb, b, s, out, M);
  } else {
    dim3 fgrid(N_OUT / FBN, (M + FBM - 1) / FBM);
    gemm_fused_kernel<<<fgrid, 256, 0, stream>>>(x, W, b, out, M);
    scatter_kernel<<<(E + 255) / 256, 256, 0, stream>>>(x, ei, out, E);
  }
}

// Round 9
// 421.945 us; speedup vs baseline: 1.0853x; 1.0211x over previous
//
#include <hip/hip_runtime.h>
#include <stdint.h>

#define K_DIM 512
#define N_OUT 512
#define BM 64
#define BN 128
#define BK 32
#define NT 16  // K_DIM / BK tiles

typedef __bf16 bf16x8 __attribute__((ext_vector_type(8)));
typedef float f32x4 __attribute__((ext_vector_type(4)));
typedef unsigned short ushort8 __attribute__((ext_vector_type(8)));

__device__ inline unsigned short f2bf(float f) {
  unsigned u = __float_as_uint(f);
  u += 0x7fffu + ((u >> 16) & 1u);
  return (unsigned short)(u >> 16);
}

// ---------------- prep (grid-stride): cvt x->xb, cvt W->wb, zero s, densify x0 --
__global__ __launch_bounds__(256) void prep_all_kernel(
    const float* __restrict__ x, unsigned short* __restrict__ xb,
    const float* __restrict__ W, unsigned short* __restrict__ wb,
    float* __restrict__ x0, float* __restrict__ s,
    int n8x, int n8w, int n8s) {
  const int stride = gridDim.x * 256;
  const int total = n8x + n8w + n8s;
  for (int i = blockIdx.x * 256 + threadIdx.x; i < total; i += stride) {
    if (i < n8x) {
      const f32x4* sp = (const f32x4*)x + (size_t)i * 2;
      f32x4 a = __builtin_nontemporal_load(sp);
      f32x4 c = __builtin_nontemporal_load(sp + 1);
      ushort8 o;
      o[0] = f2bf(a[0]); o[1] = f2bf(a[1]); o[2] = f2bf(a[2]); o[3] = f2bf(a[3]);
      o[4] = f2bf(c[0]); o[5] = f2bf(c[1]); o[6] = f2bf(c[2]); o[7] = f2bf(c[3]);
      *(ushort8*)(xb + (size_t)i * 8) = o;
      if ((i & 63) == 0) x0[i >> 6] = a[0];  // densify col 0 (row r at chunk 64r)
    } else if (i < n8x + n8w) {
      int j = i - n8x;
      const f32x4* sp = (const f32x4*)W + (size_t)j * 2;
      f32x4 a = sp[0], c = sp[1];
      ushort8 o;
      o[0] = f2bf(a[0]); o[1] = f2bf(a[1]); o[2] = f2bf(a[2]); o[3] = f2bf(a[3]);
      o[4] = f2bf(c[0]); o[5] = f2bf(c[1]); o[6] = f2bf(c[2]); o[7] = f2bf(c[3]);
      *(ushort8*)(wb + (size_t)j * 8) = o;
    } else {
      int j = i - n8x - n8w;
      f32x4 z = {0.f, 0.f, 0.f, 0.f};
      *(f32x4*)(s + (size_t)j * 8) = z;
      *(f32x4*)(s + (size_t)j * 8 + 4) = z;
    }
  }
}

// ---------------- scatter pre-pass: s[col[e]] += x0[e] (coalesced read) ---------
__global__ __launch_bounds__(256) void scatter_s_kernel(const float* __restrict__ x0,
                                                        const int* __restrict__ ei,
                                                        float* __restrict__ s, int E) {
  int e = blockIdx.x * 256 + threadIdx.x;
  if (e < E) {
    atomicAdd(s + ei[E + e], x0[e]);
  }
}

// ---------------- GEMM: counted-vmcnt core at 64x128, BK=32, 5 blocks/CU --------
// LDS 24KB (A 2x4KB + B 2x8KB) + launch_bounds(256,5) -> 5 blocks/CU, 5 waves/SIMD
// (R8 had 3): more independent blocks per SIMD fill barrier/latency gaps.
// Ledger: 3 glds/tile/thread (1 A + 2 B); 2-deep prefetch; per-tile vmcnt(3).
// Known cost: 64B row stride -> 2-bit XOR space -> 4-way bank conflict on
// fragment ds_reads (~1.58x on a small fraction of the phase) - accepted.
__global__ __launch_bounds__(256, 5) void gemm_bf16_kernel(
    const unsigned short* __restrict__ xb, const unsigned short* __restrict__ wb,
    const float* __restrict__ b, const float* __restrict__ s,
    float* __restrict__ out, int M) {
  __shared__ __align__(16) unsigned short Als[2][BM * BK];  // 2 x 4 KB
  __shared__ __align__(16) unsigned short Bls[2][BN * BK];  // 2 x 8 KB

  const int tid = threadIdx.x;
  const int lane = tid & 63;
  const int quad = lane >> 4;
  const int l16 = lane & 15;
  const int waveId = tid >> 6;
  const int wm = (waveId >> 1) * 32;  // wave tile 32x64 of the 64x128 block
  const int wn = (waveId & 1) * 64;

  // m204 bijective XCD remap: the 4 column-tiles of one x row-band run
  // consecutively on one XCD -> A-panel L2-served.
  const int nwg = gridDim.x * gridDim.y;  // 6252
  int raw = blockIdx.y * gridDim.x + blockIdx.x;
  int q = nwg >> 3, r = nwg & 7;
  int xcd = raw & 7;
  int wg = (xcd < r ? xcd * (q + 1) : r * (q + 1) + (xcd - r) * q) + (raw >> 3);
  const int blockM = (wg >> 2) * BM;  // gridDim.x == N_OUT/BN == 4
  const int blockN = (wg & 3) * BN;

  // staging: thread owns lane-contiguous 16B chunks (global_load_lds layout);
  // global source chunk XOR-swizzled (2-bit space at 64B rows).
  size_t goffA, goffB[2];
  int ldsoffA, ldsoffB[2];
  {
    int ch = tid;                // 256 A-chunks: 64 rows x 4
    int row = ch >> 2;
    int c4 = ch & 3;
    int sc = c4 ^ (row & 3);
    int ga_row = blockM + row;
    if (ga_row > M - 1) ga_row = M - 1;  // clamp tail (masked in epilogue)
    goffA = (size_t)ga_row * K_DIM + sc * 8;
    ldsoffA = ch * 8;
  }
#pragma unroll
  for (int i = 0; i < 2; ++i) {
    int ch = i * 256 + tid;      // 512 B-chunks: 128 rows x 4
    int row = ch >> 2;
    int c4 = ch & 3;
    int sc = c4 ^ (row & 3);
    goffB[i] = (size_t)(blockN + row) * K_DIM + sc * 8;
    ldsoffB[i] = ch * 8;
  }

#define STAGE(buf, k0)                                                               \
  {                                                                                  \
    __builtin_amdgcn_global_load_lds(                                                \
        (const __attribute__((address_space(1))) void*)(xb + goffA + (k0)),          \
        (__attribute__((address_space(3))) void*)(&Als[buf][ldsoffA]), 16, 0, 0);    \
    _Pragma("unroll") for (int i = 0; i < 2; ++i) {                                  \
      __builtin_amdgcn_global_load_lds(                                              \
          (const __attribute__((address_space(1))) void*)(wb + goffB[i] + (k0)),     \
          (__attribute__((address_space(3))) void*)(&Bls[buf][ldsoffB[i]]), 16, 0, 0);\
    }                                                                                \
  }

  f32x4 acc[2][4] = {};

  // prologue: tiles 0 and 1 in flight (6 loads/thread)
  STAGE(0, 0);
  STAGE(1, BK);

#pragma unroll
  for (int t = 0; t < NT; ++t) {
    // counted wait: tile t's 3 loads done; tile t+1's 3 remain in flight
    if (t < NT - 1) {
      asm volatile("s_waitcnt vmcnt(3)" ::: "memory");
    } else {
      asm volatile("s_waitcnt vmcnt(0)" ::: "memory");
    }
    __builtin_amdgcn_s_barrier();

    const int cur = t & 1;
    // single K=32 step
    bf16x8 af[2], bfr[4];
#pragma unroll
    for (int mi = 0; mi < 2; ++mi) {
      int rr = wm + mi * 16 + l16;
      int c = quad ^ (rr & 3);
      af[mi] = *(const bf16x8*)(&Als[cur][rr * BK + c * 8]);
    }
#pragma unroll
    for (int ni = 0; ni < 4; ++ni) {
      int rr = wn + ni * 16 + l16;
      int c = quad ^ (rr & 3);
      bfr[ni] = *(const bf16x8*)(&Bls[cur][rr * BK + c * 8]);
    }
    __builtin_amdgcn_s_setprio(1);
#pragma unroll
    for (int mi = 0; mi < 2; ++mi)
#pragma unroll
      for (int ni = 0; ni < 4; ++ni)
        acc[mi][ni] = __builtin_amdgcn_mfma_f32_16x16x32_bf16(af[mi], bfr[ni], acc[mi][ni], 0, 0, 0);
    __builtin_amdgcn_s_setprio(0);

    // all waves done reading buf[cur]
    __builtin_amdgcn_s_barrier();
    if (t + 2 < NT) {
      STAGE(cur, (t + 2) * BK);  // refill freed buffer; back to 6 in flight
    }
  }
#undef STAGE

  // epilogue: bias + relu + scatter-add (col 0); C/D layout col=lane&15,
  // row=quad*4+reg (m89/m91). Nontemporal: out never re-read; keep xb in L3.
#pragma unroll
  for (int ni = 0; ni < 4; ++ni) {
    int gcol = blockN + wn + ni * 16 + l16;
    float bias = b[gcol];
#pragma unroll
    for (int mi = 0; mi < 2; ++mi) {
#pragma unroll
      for (int rr = 0; rr < 4; ++rr) {
        int grow = blockM + wm + mi * 16 + quad * 4 + rr;
        if (grow < M) {
          float v = acc[mi][ni][rr] + bias;
          v = v > 0.f ? v : 0.f;
          if (gcol == 0) v += s[grow];  // relu first, then scatter-add (matches ref)
          __builtin_nontemporal_store(v, out + (size_t)grow * N_OUT + gcol);
        }
      }
    }
  }
}

// ---------------- fallback: fused-conversion GEMM (if ws too small) -------------
#define FBM 128
#define FBN 128
#define LDS_STRIDE 40
__global__ __launch_bounds__(256) void gemm_fused_kernel(
    const float* __restrict__ x, const float* __restrict__ W,
    const float* __restrict__ b, float* __restrict__ out, int M) {
  __shared__ __align__(16) unsigned short Als[FBM * LDS_STRIDE];
  __shared__ __align__(16) unsigned short Bls[FBN * LDS_STRIDE];
  const int tid = threadIdx.x;
  const int lane = tid & 63;
  const int quad = lane >> 4;
  const int l16 = lane & 15;
  const int waveId = tid >> 6;
  const int wm = (waveId >> 1) * 64;
  const int wn = (waveId & 1) * 64;
  const int blockM = blockIdx.y * FBM;
  const int blockN = blockIdx.x * FBN;
  f32x4 acc[4][4] = {};
  for (int k0 = 0; k0 < K_DIM; k0 += 32) {
#pragma unroll
    for (int i = 0; i < 4; ++i) {
      int idx = i * 256 + tid;
      int row = idx >> 3;
      int c4 = idx & 7;
      float4 va = make_float4(0.f, 0.f, 0.f, 0.f);
      int grow = blockM + row;
      if (grow < M) va = *(const float4*)(x + (size_t)grow * K_DIM + k0 + c4 * 4);
      ushort4 ha;
      ha.x = f2bf(va.x); ha.y = f2bf(va.y); ha.z = f2bf(va.z); ha.w = f2bf(va.w);
      *(ushort4*)(&Als[row * LDS_STRIDE + c4 * 4]) = ha;
      float4 vb = *(const float4*)(W + (size_t)(blockN + row) * K_DIM + k0 + c4 * 4);
      ushort4 hb;
      hb.x = f2bf(vb.x); hb.y = f2bf(vb.y); hb.z = f2bf(vb.z); hb.w = f2bf(vb.w);
      *(ushort4*)(&Bls[row * LDS_STRIDE + c4 * 4]) = hb;
    }
    __syncthreads();
    bf16x8 af[4], bfr[4];
#pragma unroll
    for (int mi = 0; mi < 4; ++mi)
      af[mi] = *(const bf16x8*)(&Als[(wm + mi * 16 + l16) * LDS_STRIDE + quad * 8]);
#pragma unroll
    for (int ni = 0; ni < 4; ++ni)
      bfr[ni] = *(const bf16x8*)(&Bls[(wn + ni * 16 + l16) * LDS_STRIDE + quad * 8]);
#pragma unroll
    for (int mi = 0; mi < 4; ++mi)
#pragma unroll
      for (int ni = 0; ni < 4; ++ni)
        acc[mi][ni] = __builtin_amdgcn_mfma_f32_16x16x32_bf16(af[mi], bfr[ni], acc[mi][ni], 0, 0, 0);
    __syncthreads();
  }
#pragma unroll
  for (int ni = 0; ni < 4; ++ni) {
    int gcol = blockN + wn + ni * 16 + l16;
    float bias = b[gcol];
#pragma unroll
    for (int mi = 0; mi < 4; ++mi) {
#pragma unroll
      for (int rr = 0; rr < 4; ++rr) {
        int grow = blockM + wm + mi * 16 + quad * 4 + rr;
        if (grow < M) {
          float v = acc[mi][ni][rr] + bias;
          out[(size_t)grow * N_OUT + gcol] = v > 0.f ? v : 0.f;
        }
      }
    }
  }
}

// fallback scatter: out[col[e], 0] += x[e, 0]
__global__ void scatter_kernel(const float* __restrict__ x,
                               const int* __restrict__ ei,
                               float* __restrict__ out, int E) {
  int e = blockIdx.x * 256 + threadIdx.x;
  if (e < E) {
    int c = ei[E + e];
    atomicAdd(out + (size_t)c * N_OUT, x[(size_t)e * K_DIM]);
  }
}

extern "C" void kernel_launch(void* const* d_in, const int* in_sizes, int n_in,
                              void* d_out, int out_size, void* d_ws, size_t ws_size,
                              hipStream_t stream) {
  const float* x = (const float*)d_in[0];
  const int* ei = (const int*)d_in[1];
  const float* W = (const float*)d_in[2];
  const float* b = (const float*)d_in[3];
  float* out = (float*)d_out;

  int M = in_sizes[0] / K_DIM;  // 100000
  int E = in_sizes[1] / 2;      // 100000

  size_t x_elems = (size_t)M * K_DIM;      // 51,200,000
  size_t w_elems = (size_t)N_OUT * K_DIM;  // 262,144
  int n8x = (int)(x_elems / 8);            // 6,400,000
  int n8w = (int)(w_elems / 8);            // 32,768
  int n8s = (M + 7) / 8;                   // 12,500
  size_t s_elems = (size_t)n8s * 8;

  // ws layout: xb (bf16) | wb (bf16) | s (f32) | x0 (f32)
  size_t need = x_elems * 2 + w_elems * 2 + s_elems * 4 + (size_t)M * 4;

  dim3 grid(N_OUT / BN, (M + BM - 1) / BM);  // (4, 1563) -> nwg=6252

  if (ws_size >= need) {
    unsigned short* xb = (unsigned short*)d_ws;
    unsigned short* wb = xb + x_elems;
    float* s = (float*)(wb + w_elems);
    float* x0 = s + s_elems;

    int total = n8x + n8w + n8s;
    int pblk = (total + 255) / 256;
    if (pblk > 2048) pblk = 2048;  // grid-stride
    prep_all_kernel<<<pblk, 256, 0, stream>>>(x, xb, W, wb, x0, s, n8x, n8w, n8s);
    scatter_s_kernel<<<(E + 255) / 256, 256, 0, stream>>>(x0, ei, s, E);
    gemm_bf16_kernel<<<grid, 256, 0, stream>>>(xb, wb, b, s, out, M);
  } else {
    dim3 fgrid(N_OUT / FBN, (M + FBM - 1) / FBM);
    gemm_fused_kernel<<<fgrid, 256, 0, stream>>>(x, W, b, out, M);
    scatter_kernel<<<(E + 255) / 256, 256, 0, stream>>>(x, ei, out, E);
  }
}